// Round 16
// baseline (174.191 us; speedup 1.0000x reference)
//
#include <hip/hip_runtime.h>
#include <hip/hip_bf16.h>

typedef __attribute__((ext_vector_type(8))) short short8;
typedef __attribute__((ext_vector_type(4))) float f32x4;

#define MFMA16(a,b,c) __builtin_amdgcn_mfma_f32_16x16x32_bf16((a),(b),(c),0,0,0)

static __device__ __forceinline__ unsigned short f2b(float f){
  __hip_bfloat16 h = __float2bfloat16(f);
  return __builtin_bit_cast(unsigned short, h);
}
static __device__ __forceinline__ float b2f(unsigned short u){
  unsigned int v = ((unsigned int)u)<<16;
  return __builtin_bit_cast(float, v);
}

static __device__ __forceinline__ void gld_lds16(const void* g, void* l){
  __builtin_amdgcn_global_load_lds((const __attribute__((address_space(1))) unsigned int*)g,
                                   (__attribute__((address_space(3))) unsigned int*)l, 16, 0, 0);
}

// ---------------- fused prep: convert x + transpose-convert both weights ----------------
__global__ __launch_bounds__(256) void k_prep(const float* __restrict__ x,
    const float* __restrict__ wA, const float* __restrict__ wP,
    unsigned short* __restrict__ xb, unsigned short* __restrict__ wtA,
    unsigned short* __restrict__ wtP){
  int bid = blockIdx.x, tid = threadIdx.x;
  if (bid < 4096){
    int i = (bid*256 + tid)*8;
    float4 a = *(const float4*)(x+i);
    float4 b = *(const float4*)(x+i+4);
    short8 v;
    v[0]=f2b(a.x); v[1]=f2b(a.y); v[2]=f2b(a.z); v[3]=f2b(a.w);
    v[4]=f2b(b.x); v[5]=f2b(b.y); v[6]=f2b(b.z); v[7]=f2b(b.w);
    *(short8*)(xb+i) = v;
    return;
  }
  __shared__ float tile[32][33];
  const float* in; unsigned short* out; int R, C, bx, by;
  if (bid < 10240){ int tt = bid-4096;  in=wA; out=wtA; R=2048; C=3072; bx=tt%96; by=tt/96; }
  else            { int tt = bid-10240; in=wP; out=wtP; R=2048; C=2048; bx=tt%64; by=tt/64; }
  int c0 = bx*32, r0 = by*32;
  int tx = tid&31, ty = tid>>5;
  #pragma unroll
  for (int i=0;i<4;i++) tile[ty*4+i][tx] = in[(size_t)(r0+ty*4+i)*C + c0+tx];
  __syncthreads();
  #pragma unroll
  for (int i=0;i<4;i++) out[(size_t)(c0+ty*4+i)*R + r0+tx] = f2b(tile[tx][ty*4+i]);
}

// ---------------- 128x128 m97-structure bf16 GEMM: C = A[M][K] * BT[N][K]^T ----------------
template<int OB>   // OB=1: bf16 C out, OB=0: f32 C out
__global__ __launch_bounds__(256,2) void k_gemm97(const unsigned short* __restrict__ A,
    const unsigned short* __restrict__ BT, void* __restrict__ Cv,
    int M, int N, int K, int nbx){
  __shared__ __align__(16) unsigned short As[128*64];
  __shared__ __align__(16) unsigned short Bs[128*64];
  const int NT = K >> 6;
  int cpx = gridDim.x >> 3;
  int bid = blockIdx.x;
  int swz = (bid & 7)*cpx + (bid >> 3);
  int bm = (swz / nbx)*128, bn = (swz % nbx)*128;
  int tid = threadIdx.x;
  int wave = tid >> 6, lane = tid & 63;
  int r = lane & 15, g = lane >> 4;
  int wr = (wave >> 1)*64, wc = (wave & 1)*64;
  int sw = r & 7;

  f32x4 acc[4][4];
  #pragma unroll
  for (int i=0;i<4;i++)
    #pragma unroll
    for (int j=0;j<4;j++){ acc[i][j][0]=0.f; acc[i][j][1]=0.f; acc[i][j][2]=0.f; acc[i][j][3]=0.f; }

  for (int t=0; t<NT; ++t){
    #pragma unroll
    for (int i=0;i<4;i++){
      int c = i*256 + tid;
      int row = c>>3, kc = c&7;
      gld_lds16(&A[(size_t)(bm+row)*K + (size_t)t*64 + ((kc^(row&7))*8)], (char*)As + c*16);
    }
    #pragma unroll
    for (int i=0;i<4;i++){
      int c = i*256 + tid;
      int row = c>>3, kc = c&7;
      gld_lds16(&BT[(size_t)(bn+row)*K + (size_t)t*64 + ((kc^(row&7))*8)], (char*)Bs + c*16);
    }
    __syncthreads();
    short8 af[4][2], bf[4][2];
    #pragma unroll
    for (int i=0;i<4;i++)
      #pragma unroll
      for (int kk=0;kk<2;kk++){
        int row = wr + i*16 + r;
        af[i][kk] = *(const short8*)((const char*)As + ((size_t)(row*8 + ((kk*4+g)^sw))<<4));
      }
    #pragma unroll
    for (int j=0;j<4;j++)
      #pragma unroll
      for (int kk=0;kk<2;kk++){
        int row = wc + j*16 + r;
        bf[j][kk] = *(const short8*)((const char*)Bs + ((size_t)(row*8 + ((kk*4+g)^sw))<<4));
      }
    #pragma unroll
    for (int kk=0;kk<2;kk++)
      #pragma unroll
      for (int i=0;i<4;i++)
        #pragma unroll
        for (int j=0;j<4;j++)
          acc[i][j] = MFMA16(af[i][kk], bf[j][kk], acc[i][j]);
    __syncthreads();
  }

  #pragma unroll
  for (int i=0;i<4;i++)
    #pragma unroll
    for (int j=0;j<4;j++)
      #pragma unroll
      for (int rr=0;rr<4;rr++){
        size_t idx = (size_t)(bm + wr + i*16 + 4*g + rr)*N + bn + wc + j*16 + r;
        if (OB) ((unsigned short*)Cv)[idx] = f2b(acc[i][j][rr]);
        else    ((float*)Cv)[idx] = acc[i][j][rr];
      }
}

// ---------------- mid: K-rope (bid<4096) + V transpose (bid>=4096) ----------------
__global__ __launch_bounds__(256) void k_mid(const unsigned short* __restrict__ qkv,
    const float* __restrict__ fc, unsigned short* __restrict__ kb,
    unsigned short* __restrict__ vt){
  int bid = blockIdx.x, tid = threadIdx.x;
  if (bid < 4096){
    int row = bid;                 // b*2048 + t
    int t = row & 2047, b = row >> 11;
    const unsigned short* qr = qkv + (size_t)row*3072 + 2048;
    int kh = tid>>6, f = tid&63;
    unsigned int pr = *(const unsigned int*)&qr[kh*128 + 2*f];
    float x0 = b2f((unsigned short)(pr & 0xffff)), x1 = b2f((unsigned short)(pr >> 16));
    float2 cssn = *(const float2*)&fc[t*128 + 2*f];
    float o0 = x0*cssn.x - x1*cssn.y, o1 = x0*cssn.y + x1*cssn.x;
    size_t o = ((size_t)(b*4 + kh)*2048 + t)*128 + 2*f;
    kb[o] = f2b(o0); kb[o+1] = f2b(o1);
    return;
  }
  __shared__ unsigned short tile[32][33];
  int tt = bid - 4096;             // 2048 blocks: (x4, y64, z8)
  int xx = tt & 3, yy = (tt>>2) & 63, bk = tt >> 8;
  int d0 = xx*32, t0 = yy*32;
  int tx = tid & 31, ty = tid >> 5;
  const unsigned short* vp = qkv + (size_t)(bk>>2)*2048*3072 + 2560 + (bk&3)*128;
  unsigned short* vtp = vt + (size_t)bk*128*2048;
  #pragma unroll
  for (int i=0;i<4;i++) tile[ty*4+i][tx] = vp[(size_t)(t0+ty*4+i)*3072 + d0+tx];
  __syncthreads();
  #pragma unroll
  for (int i=0;i<4;i++) vtp[(size_t)(d0+ty*4+i)*2048 + t0+tx] = tile[tx][ty*4+i];
}

// ---------------- sliding-window flash attention, two q-strips per wave ----------------
// KVBLK=32 diet: Ks 2x8K + Vs 2x8K + plds 5.1K = 37.1KB -> 3 blocks/CU (+50% TLP).
// Per tile: 16 MFMA (8 QK + 8 PV) x 2 strips halved; shuffle-free defer-max;
// Q-rope fused at load; balanced XOR swizzles (K: rows 256B xor8; V: rows 64B xor4).
__global__ __launch_bounds__(256,3) void k_attn(const unsigned short* __restrict__ qkv,
    const float* __restrict__ fc, const unsigned short* __restrict__ k,
    const unsigned short* __restrict__ vt, unsigned short* __restrict__ y){
  int qb0 = blockIdx.x*128;
  int h = blockIdx.y, b = blockIdx.z;
  int kvh = h>>2;
  int tid = threadIdx.x, wave = tid>>6, lane = tid&63;
  int w0A = qb0 + wave*32, w0B = w0A + 16;
  int r = lane&15, g = lane>>4;
  const unsigned short* qsrc = qkv + (size_t)(b*2048)*3072 + h*128;
  const unsigned short* kh = k + ((size_t)(b*4+kvh)*2048)*128;
  const unsigned short* vh = vt + ((size_t)(b*4+kvh)*128)*2048;

  __shared__ unsigned short Ks[2][32*128];   // [key][d], 256B rows, xor8 swizzled
  __shared__ unsigned short Vs[2][128*32];   // [d][key], 64B rows, xor4 swizzled
  __shared__ unsigned short plds[4][16][40]; // 80B stride

  const float QS = 0.12751743f;    // log2(e)/sqrt(128)
  short8 qfA[4], qfB[4];
  {
    int tA = w0A + r, tB = w0B + r;
    const float* fcA = fc + (size_t)tA*128;
    const float* fcB = fc + (size_t)tB*128;
    #pragma unroll
    for (int c=0;c<4;c++){
      int d0 = c*32 + g*8;
      short8 rawA = *(const short8*)&qsrc[(size_t)tA*3072 + d0];
      short8 rawB = *(const short8*)&qsrc[(size_t)tB*3072 + d0];
      short8 oA, oB;
      #pragma unroll
      for (int j=0;j<4;j++){
        float a0 = b2f((unsigned short)rawA[2*j]), a1 = b2f((unsigned short)rawA[2*j+1]);
        float b0 = b2f((unsigned short)rawB[2*j]), b1 = b2f((unsigned short)rawB[2*j+1]);
        float2 csA = *(const float2*)&fcA[d0 + 2*j];
        float2 csB = *(const float2*)&fcB[d0 + 2*j];
        oA[2*j]   = (short)f2b((a0*csA.x - a1*csA.y)*QS);
        oA[2*j+1] = (short)f2b((a0*csA.y + a1*csA.x)*QS);
        oB[2*j]   = (short)f2b((b0*csB.x - b1*csB.y)*QS);
        oB[2*j+1] = (short)f2b((b0*csB.y + b1*csB.x)*QS);
      }
      qfA[c] = oA; qfB[c] = oB;
    }
  }

  f32x4 accA[8], accB[8];
  #pragma unroll
  for (int d=0; d<8; d++){
    accA[d][0]=0.f; accA[d][1]=0.f; accA[d][2]=0.f; accA[d][3]=0.f;
    accB[d][0]=0.f; accB[d][1]=0.f; accB[d][2]=0.f; accB[d][3]=0.f;
  }
  float mA[4]  = {-1e30f,-1e30f,-1e30f,-1e30f};
  float mB[4]  = {-1e30f,-1e30f,-1e30f,-1e30f};
  float lsA[4] = {0.f,0.f,0.f,0.f};
  float lsB[4] = {0.f,0.f,0.f,0.f};

  int lo = qb0 - 511; if (lo < 0) lo = 0;
  int t0 = lo & ~31;
  int nt = ((qb0 + 127) - t0)/32 + 1;
  int swk = (r&7)<<4;                // K read swizzle (rows 256B)
  int swv = (r&3)<<4;                // V read swizzle (rows 64B)

  #define STAGE(bb, kt)                                                          \
    { _Pragma("unroll")                                                          \
      for (int p=0;p<2;p++){                                                     \
        int c = p*256 + tid;                                                     \
        int row = c>>4, col = (c&15)*16;                                         \
        gld_lds16((const char*)kh + (size_t)((kt)+row)*256 + (col ^ ((row&7)<<4)),\
                  (char*)&Ks[bb][0] + c*16);                                     \
      }                                                                          \
      _Pragma("unroll")                                                          \
      for (int p=0;p<2;p++){                                                     \
        int c = p*256 + tid;                                                     \
        int row = c>>2, col = (c&3)*16;                                          \
        gld_lds16((const char*)vh + (size_t)row*4096 + (size_t)(kt)*2 + (col ^ ((row&3)<<4)),\
                  (char*)&Vs[bb][0] + c*16);                                     \
      }                                                                          \
    }

  STAGE(0, t0);
  __syncthreads();
  int cur = 0;

  for (int it=0; it<nt; it++){
    int kt = t0 + it*32;
    if (it+1 < nt) STAGE(cur^1, kt + 32);

    bool useA = (kt <= w0A+15) && (kt+31 >= w0A-511);
    bool useB = (kt <= w0B+15) && (kt+31 >= w0B-511);
    if (useA || useB){
      f32x4 SA[2], SB[2];
      __builtin_amdgcn_s_setprio(1);
      #pragma unroll
      for (int s=0;s<2;s++){
        f32x4 aA; aA[0]=0.f; aA[1]=0.f; aA[2]=0.f; aA[3]=0.f;
        f32x4 aB; aB[0]=0.f; aB[1]=0.f; aB[2]=0.f; aB[3]=0.f;
        const char* kr = (const char*)&Ks[cur][0] + (s*16+r)*256;
        #pragma unroll
        for (int c=0;c<4;c++){
          short8 kf = *(const short8*)(kr + ((c*64 + g*16) ^ swk));
          aA = MFMA16(qfA[c], kf, aA);
          aB = MFMA16(qfB[c], kf, aB);
        }
        SA[s] = aA; SB[s] = aB;
      }
      __builtin_amdgcn_s_setprio(0);
      // mask + in-lane max only (no cross-lane ops on the common path)
      bool fullA = (kt+31 <= w0A) && (kt >= w0A-496);
      bool fullB = (kt+31 <= w0B) && (kt >= w0B-496);
      float lmA[4], lmB[4];
      if (fullA){
        #pragma unroll
        for (int rr=0;rr<4;rr++) lmA[rr] = fmaxf(SA[0][rr], SA[1][rr]);
      } else {
        #pragma unroll
        for (int rr=0;rr<4;rr++){
          int baseA = w0A + 4*g + rr - kt;
          float ma = -3e38f;
          #pragma unroll
          for (int s=0;s<2;s++){
            int dd = baseA - s*16 - r;
            float sa = ((unsigned)dd < 512u) ? SA[s][rr] : -3e38f;
            SA[s][rr] = sa;
            ma = fmaxf(ma, sa);
          }
          lmA[rr] = ma;
        }
      }
      if (fullB){
        #pragma unroll
        for (int rr=0;rr<4;rr++) lmB[rr] = fmaxf(SB[0][rr], SB[1][rr]);
      } else {
        #pragma unroll
        for (int rr=0;rr<4;rr++){
          int baseB = w0B + 4*g + rr - kt;
          float mb_ = -3e38f;
          #pragma unroll
          for (int s=0;s<2;s++){
            int dd = baseB - s*16 - r;
            float sb = ((unsigned)dd < 512u) ? SB[s][rr] : -3e38f;
            SB[s][rr] = sb;
            mb_ = fmaxf(mb_, sb);
          }
          lmB[rr] = mb_;
        }
      }
      // shuffle-free defer-max gate
      bool okA = true, okB = true;
      #pragma unroll
      for (int rr=0;rr<4;rr++){
        okA = okA && (lmA[rr] - mA[rr] <= 8.f);
        okB = okB && (lmB[rr] - mB[rr] <= 8.f);
      }
      if (!__all(okA)){
        float mxA[4];
        #pragma unroll
        for (int rr=0;rr<4;rr++) mxA[rr] = lmA[rr];
        #pragma unroll
        for (int st=1; st<16; st<<=1)
          #pragma unroll
          for (int rr=0;rr<4;rr++)
            mxA[rr] = fmaxf(mxA[rr], __shfl_xor(mxA[rr], st));
        #pragma unroll
        for (int rr=0;rr<4;rr++){
          float mn = fmaxf(mA[rr], mxA[rr]);
          float al = exp2f(mA[rr] - mn);
          mA[rr] = mn;
          lsA[rr] *= al;
          #pragma unroll
          for (int d=0;d<8;d++) accA[d][rr] *= al;
        }
      }
      if (!__all(okB)){
        float mxB[4];
        #pragma unroll
        for (int rr=0;rr<4;rr++) mxB[rr] = lmB[rr];
        #pragma unroll
        for (int st=1; st<16; st<<=1)
          #pragma unroll
          for (int rr=0;rr<4;rr++)
            mxB[rr] = fmaxf(mxB[rr], __shfl_xor(mxB[rr], st));
        #pragma unroll
        for (int rr=0;rr<4;rr++){
          float mn = fmaxf(mB[rr], mxB[rr]);
          float al = exp2f(mB[rr] - mn);
          mB[rr] = mn;
          lsB[rr] *= al;
          #pragma unroll
          for (int d=0;d<8;d++) accB[d][rr] *= al;
        }
      }
      #pragma unroll
      for (int rr=0;rr<4;rr++){
        float psA = 0.f, psB = 0.f;
        #pragma unroll
        for (int s=0;s<2;s++){
          float pa = exp2f(SA[s][rr] - mA[rr]);
          float pb = exp2f(SB[s][rr] - mB[rr]);
          SA[s][rr] = pa; SB[s][rr] = pb;
          psA += pa; psB += pb;
        }
        lsA[rr] += psA;
        lsB[rr] += psB;
      }
      // ---- strip A relayout + PV-A ----
      #pragma unroll
      for (int rr=0;rr<4;rr++)
        #pragma unroll
        for (int s=0;s<2;s++)
          plds[wave][4*g+rr][s*16+r] = f2b(SA[s][rr]);
      short8 pfA = *(const short8*)&plds[wave][r][g*8];
      __builtin_amdgcn_s_setprio(1);
      #pragma unroll
      for (int d=0;d<8;d++){
        const char* vr = (const char*)&Vs[cur][0] + (d*16+r)*64;
        short8 vf = *(const short8*)(vr + ((g*16) ^ swv));
        accA[d] = MFMA16(pfA, vf, accA[d]);
      }
      __builtin_amdgcn_s_setprio(0);
      // ---- strip B relayout + PV-B ----
      #pragma unroll
      for (int rr=0;rr<4;rr++)
        #pragma unroll
        for (int s=0;s<2;s++)
          plds[wave][4*g+rr][s*16+r] = f2b(SB[s][rr]);
      short8 pfB = *(const short8*)&plds[wave][r][g*8];
      __builtin_amdgcn_s_setprio(1);
      #pragma unroll
      for (int d=0;d<8;d++){
        const char* vr = (const char*)&Vs[cur][0] + (d*16+r)*64;
        short8 vf = *(const short8*)(vr + ((g*16) ^ swv));
        accB[d] = MFMA16(pfB, vf, accB[d]);
      }
      __builtin_amdgcn_s_setprio(0);
    }
    __syncthreads();
    cur ^= 1;
  }

  #pragma unroll
  for (int rr=0;rr<4;rr++){
    float sa = lsA[rr], sb = lsB[rr];
    #pragma unroll
    for (int st=1; st<16; st<<=1){ sa += __shfl_xor(sa, st); sb += __shfl_xor(sb, st); }
    float invA = 1.f/sa, invB = 1.f/sb;
    int iA = w0A + 4*g + rr, iB = w0B + 4*g + rr;
    #pragma unroll
    for (int d=0;d<8;d++){
      y[((size_t)(b*2048)+iA)*2048 + h*128 + d*16 + r] = f2b(accA[d][rr]*invA);
      y[((size_t)(b*2048)+iB)*2048 + h*128 + d*16 + r] = f2b(accB[d][rr]*invB);
    }
  }
}

extern "C" void kernel_launch(void* const* d_in, const int* in_sizes, int n_in,
                              void* d_out, int out_size, void* d_ws, size_t ws_size,
                              hipStream_t stream) {
  const float* x      = (const float*)d_in[0];
  const float* w_attn = (const float*)d_in[1];
  const float* w_proj = (const float*)d_in[2];
  const float* fc     = (const float*)d_in[3];
  float* out = (float*)d_out;
  char* ws = (char*)d_ws;
  unsigned short* xb   = (unsigned short*)(ws);             // 16,777,216
  unsigned short* wtA  = (unsigned short*)(ws + 16777216);  // 12,582,912
  unsigned short* wtP  = (unsigned short*)(ws + 29360128);  //  8,388,608
  unsigned short* qkvb = (unsigned short*)(ws + 37748736);  // 25,165,824
  unsigned short* yb   = (unsigned short*)(ws + 62914560);  // 16,777,216
  unsigned short* kb   = (unsigned short*)(ws + 79691776);  //  4,194,304
  unsigned short* vtb  = (unsigned short*)(ws + 83886080);  //  4,194,304

  k_prep<<<14336, 256, 0, stream>>>(x, w_attn, w_proj, xb, wtA, wtP);
  k_gemm97<1><<<dim3(768), 256, 0, stream>>>(xb, wtA, qkvb, 4096, 3072, 2048, 24);
  k_mid<<<6144, 256, 0, stream>>>(qkvb, fc, kb, vtb);
  k_attn<<<dim3(16,16,2), 256, 0, stream>>>(qkvb, fc, kb, vtb, yb);
  k_gemm97<0><<<dim3(512), 256, 0, stream>>>(yb, wtP, out, 4096, 2048, 2048, 16);
}

// Round 17
// 164.305 us; speedup vs baseline: 1.0602x; 1.0602x over previous
//
#include <hip/hip_runtime.h>
#include <hip/hip_bf16.h>

typedef __attribute__((ext_vector_type(8))) short short8;
typedef __attribute__((ext_vector_type(4))) float f32x4;

#define MFMA16(a,b,c) __builtin_amdgcn_mfma_f32_16x16x32_bf16((a),(b),(c),0,0,0)

static __device__ __forceinline__ unsigned short f2b(float f){
  __hip_bfloat16 h = __float2bfloat16(f);
  return __builtin_bit_cast(unsigned short, h);
}
static __device__ __forceinline__ float b2f(unsigned short u){
  unsigned int v = ((unsigned int)u)<<16;
  return __builtin_bit_cast(float, v);
}

static __device__ __forceinline__ void gld_lds16(const void* g, void* l){
  __builtin_amdgcn_global_load_lds((const __attribute__((address_space(1))) unsigned int*)g,
                                   (__attribute__((address_space(3))) unsigned int*)l, 16, 0, 0);
}

// ---------------- fused prep: convert x + transpose-convert both weights ----------------
__global__ __launch_bounds__(256) void k_prep(const float* __restrict__ x,
    const float* __restrict__ wA, const float* __restrict__ wP,
    unsigned short* __restrict__ xb, unsigned short* __restrict__ wtA,
    unsigned short* __restrict__ wtP){
  int bid = blockIdx.x, tid = threadIdx.x;
  if (bid < 4096){
    int i = (bid*256 + tid)*8;
    float4 a = *(const float4*)(x+i);
    float4 b = *(const float4*)(x+i+4);
    short8 v;
    v[0]=f2b(a.x); v[1]=f2b(a.y); v[2]=f2b(a.z); v[3]=f2b(a.w);
    v[4]=f2b(b.x); v[5]=f2b(b.y); v[6]=f2b(b.z); v[7]=f2b(b.w);
    *(short8*)(xb+i) = v;
    return;
  }
  __shared__ float tile[32][33];
  const float* in; unsigned short* out; int R, C, bx, by;
  if (bid < 10240){ int tt = bid-4096;  in=wA; out=wtA; R=2048; C=3072; bx=tt%96; by=tt/96; }
  else            { int tt = bid-10240; in=wP; out=wtP; R=2048; C=2048; bx=tt%64; by=tt/64; }
  int c0 = bx*32, r0 = by*32;
  int tx = tid&31, ty = tid>>5;
  #pragma unroll
  for (int i=0;i<4;i++) tile[ty*4+i][tx] = in[(size_t)(r0+ty*4+i)*C + c0+tx];
  __syncthreads();
  #pragma unroll
  for (int i=0;i<4;i++) out[(size_t)(c0+ty*4+i)*R + r0+tx] = f2b(tile[tx][ty*4+i]);
}

// ---------------- 128x128 m97-structure bf16 GEMM: C = A[M][K] * BT[N][K]^T ----------------
template<int OB>   // OB=1: bf16 C out, OB=0: f32 C out
__global__ __launch_bounds__(256,2) void k_gemm97(const unsigned short* __restrict__ A,
    const unsigned short* __restrict__ BT, void* __restrict__ Cv,
    int M, int N, int K, int nbx){
  __shared__ __align__(16) unsigned short As[128*64];
  __shared__ __align__(16) unsigned short Bs[128*64];
  const int NT = K >> 6;
  int cpx = gridDim.x >> 3;
  int bid = blockIdx.x;
  int swz = (bid & 7)*cpx + (bid >> 3);
  int bm = (swz / nbx)*128, bn = (swz % nbx)*128;
  int tid = threadIdx.x;
  int wave = tid >> 6, lane = tid & 63;
  int r = lane & 15, g = lane >> 4;
  int wr = (wave >> 1)*64, wc = (wave & 1)*64;
  int sw = r & 7;

  f32x4 acc[4][4];
  #pragma unroll
  for (int i=0;i<4;i++)
    #pragma unroll
    for (int j=0;j<4;j++){ acc[i][j][0]=0.f; acc[i][j][1]=0.f; acc[i][j][2]=0.f; acc[i][j][3]=0.f; }

  for (int t=0; t<NT; ++t){
    #pragma unroll
    for (int i=0;i<4;i++){
      int c = i*256 + tid;
      int row = c>>3, kc = c&7;
      gld_lds16(&A[(size_t)(bm+row)*K + (size_t)t*64 + ((kc^(row&7))*8)], (char*)As + c*16);
    }
    #pragma unroll
    for (int i=0;i<4;i++){
      int c = i*256 + tid;
      int row = c>>3, kc = c&7;
      gld_lds16(&BT[(size_t)(bn+row)*K + (size_t)t*64 + ((kc^(row&7))*8)], (char*)Bs + c*16);
    }
    __syncthreads();
    short8 af[4][2], bf[4][2];
    #pragma unroll
    for (int i=0;i<4;i++)
      #pragma unroll
      for (int kk=0;kk<2;kk++){
        int row = wr + i*16 + r;
        af[i][kk] = *(const short8*)((const char*)As + ((size_t)(row*8 + ((kk*4+g)^sw))<<4));
      }
    #pragma unroll
    for (int j=0;j<4;j++)
      #pragma unroll
      for (int kk=0;kk<2;kk++){
        int row = wc + j*16 + r;
        bf[j][kk] = *(const short8*)((const char*)Bs + ((size_t)(row*8 + ((kk*4+g)^sw))<<4));
      }
    #pragma unroll
    for (int kk=0;kk<2;kk++)
      #pragma unroll
      for (int i=0;i<4;i++)
        #pragma unroll
        for (int j=0;j<4;j++)
          acc[i][j] = MFMA16(af[i][kk], bf[j][kk], acc[i][j]);
    __syncthreads();
  }

  #pragma unroll
  for (int i=0;i<4;i++)
    #pragma unroll
    for (int j=0;j<4;j++)
      #pragma unroll
      for (int rr=0;rr<4;rr++){
        size_t idx = (size_t)(bm + wr + i*16 + 4*g + rr)*N + bn + wc + j*16 + r;
        if (OB) ((unsigned short*)Cv)[idx] = f2b(acc[i][j][rr]);
        else    ((float*)Cv)[idx] = acc[i][j][rr];
      }
}

// ---------------- mid: K-rope (bid<4096) + V transpose (bid>=4096) ----------------
__global__ __launch_bounds__(256) void k_mid(const unsigned short* __restrict__ qkv,
    const float* __restrict__ fc, unsigned short* __restrict__ kb,
    unsigned short* __restrict__ vt){
  int bid = blockIdx.x, tid = threadIdx.x;
  if (bid < 4096){
    int row = bid;                 // b*2048 + t
    int t = row & 2047, b = row >> 11;
    const unsigned short* qr = qkv + (size_t)row*3072 + 2048;
    int kh = tid>>6, f = tid&63;
    unsigned int pr = *(const unsigned int*)&qr[kh*128 + 2*f];
    float x0 = b2f((unsigned short)(pr & 0xffff)), x1 = b2f((unsigned short)(pr >> 16));
    float2 cssn = *(const float2*)&fc[t*128 + 2*f];
    float o0 = x0*cssn.x - x1*cssn.y, o1 = x0*cssn.y + x1*cssn.x;
    size_t o = ((size_t)(b*4 + kh)*2048 + t)*128 + 2*f;
    kb[o] = f2b(o0); kb[o+1] = f2b(o1);
    return;
  }
  __shared__ unsigned short tile[32][33];
  int tt = bid - 4096;             // 2048 blocks: (x4, y64, z8)
  int xx = tt & 3, yy = (tt>>2) & 63, bk = tt >> 8;
  int d0 = xx*32, t0 = yy*32;
  int tx = tid & 31, ty = tid >> 5;
  const unsigned short* vp = qkv + (size_t)(bk>>2)*2048*3072 + 2560 + (bk&3)*128;
  unsigned short* vtp = vt + (size_t)bk*128*2048;
  #pragma unroll
  for (int i=0;i<4;i++) tile[ty*4+i][tx] = vp[(size_t)(t0+ty*4+i)*3072 + d0+tx];
  __syncthreads();
  #pragma unroll
  for (int i=0;i<4;i++) vtp[(size_t)(d0+ty*4+i)*2048 + t0+tx] = tile[tx][ty*4+i];
}

// ---------------- sliding-window flash attention, two q-strips per wave ----------------
// K/V LDS-staged (XOR-swizzled both-sides, double-buffered, KVBLK=64); Q-rope fused
// at load; shuffle-free defer-max; interior-tile fast path; setprio on MFMA clusters.
__global__ __launch_bounds__(256,2) void k_attn(const unsigned short* __restrict__ qkv,
    const float* __restrict__ fc, const unsigned short* __restrict__ k,
    const unsigned short* __restrict__ vt, unsigned short* __restrict__ y){
  int qb0 = blockIdx.x*128;
  int h = blockIdx.y, b = blockIdx.z;
  int kvh = h>>2;
  int tid = threadIdx.x, wave = tid>>6, lane = tid&63;
  int w0A = qb0 + wave*32, w0B = w0A + 16;
  int r = lane&15, g = lane>>4;
  const unsigned short* qsrc = qkv + (size_t)(b*2048)*3072 + h*128;
  const unsigned short* kh = k + ((size_t)(b*4+kvh)*2048)*128;
  const unsigned short* vh = vt + ((size_t)(b*4+kvh)*128)*2048;

  __shared__ unsigned short Ks[2][64*128];   // [key][d], swizzled
  __shared__ unsigned short Vs[2][128*64];   // [d][key], swizzled
  __shared__ unsigned short plds[4][16][76]; // stride 152B: conflict-free g-groups

  const float QS = 0.12751743f;    // log2(e)/sqrt(128)
  short8 qfA[4], qfB[4];
  {
    int tA = w0A + r, tB = w0B + r;
    const float* fcA = fc + (size_t)tA*128;
    const float* fcB = fc + (size_t)tB*128;
    #pragma unroll
    for (int c=0;c<4;c++){
      int d0 = c*32 + g*8;
      short8 rawA = *(const short8*)&qsrc[(size_t)tA*3072 + d0];
      short8 rawB = *(const short8*)&qsrc[(size_t)tB*3072 + d0];
      short8 oA, oB;
      #pragma unroll
      for (int j=0;j<4;j++){
        float a0 = b2f((unsigned short)rawA[2*j]), a1 = b2f((unsigned short)rawA[2*j+1]);
        float b0 = b2f((unsigned short)rawB[2*j]), b1 = b2f((unsigned short)rawB[2*j+1]);
        float2 csA = *(const float2*)&fcA[d0 + 2*j];
        float2 csB = *(const float2*)&fcB[d0 + 2*j];
        oA[2*j]   = (short)f2b((a0*csA.x - a1*csA.y)*QS);
        oA[2*j+1] = (short)f2b((a0*csA.y + a1*csA.x)*QS);
        oB[2*j]   = (short)f2b((b0*csB.x - b1*csB.y)*QS);
        oB[2*j+1] = (short)f2b((b0*csB.y + b1*csB.x)*QS);
      }
      qfA[c] = oA; qfB[c] = oB;
    }
  }

  f32x4 accA[8], accB[8];
  #pragma unroll
  for (int d=0; d<8; d++){
    accA[d][0]=0.f; accA[d][1]=0.f; accA[d][2]=0.f; accA[d][3]=0.f;
    accB[d][0]=0.f; accB[d][1]=0.f; accB[d][2]=0.f; accB[d][3]=0.f;
  }
  float mA[4]  = {-1e30f,-1e30f,-1e30f,-1e30f};
  float mB[4]  = {-1e30f,-1e30f,-1e30f,-1e30f};
  float lsA[4] = {0.f,0.f,0.f,0.f};
  float lsB[4] = {0.f,0.f,0.f,0.f};

  int lo = qb0 - 511; if (lo < 0) lo = 0;
  int t0 = lo & ~63;
  int nt = ((qb0 + 127) - t0)/64 + 1;
  int sw = (r&7)<<4;                 // per-lane read swizzle

  #define STAGE(bb, kt)                                                          \
    { _Pragma("unroll")                                                          \
      for (int p=0;p<4;p++){                                                     \
        int c = p*256 + tid;                                                     \
        int row = c>>4, col = (c&15)*16;                                         \
        gld_lds16((const char*)kh + (size_t)((kt)+row)*256 + (col ^ ((row&7)<<4)),\
                  (char*)&Ks[bb][0] + c*16);                                     \
      }                                                                          \
      _Pragma("unroll")                                                          \
      for (int p=0;p<4;p++){                                                     \
        int c = p*256 + tid;                                                     \
        int row = c>>3, col = (c&7)*16;                                          \
        gld_lds16((const char*)vh + (size_t)row*4096 + (size_t)(kt)*2 + (col ^ ((row&7)<<4)),\
                  (char*)&Vs[bb][0] + c*16);                                     \
      }                                                                          \
    }

  STAGE(0, t0);
  __syncthreads();
  int cur = 0;

  for (int it=0; it<nt; it++){
    int kt = t0 + it*64;
    if (it+1 < nt) STAGE(cur^1, kt + 64);

    bool useA = (kt <= w0A+15) && (kt+63 >= w0A-511);
    bool useB = (kt <= w0B+15) && (kt+63 >= w0B-511);
    if (useA || useB){
      f32x4 SA[4], SB[4];
      __builtin_amdgcn_s_setprio(1);
      #pragma unroll
      for (int s=0;s<4;s++){
        f32x4 aA; aA[0]=0.f; aA[1]=0.f; aA[2]=0.f; aA[3]=0.f;
        f32x4 aB; aB[0]=0.f; aB[1]=0.f; aB[2]=0.f; aB[3]=0.f;
        const char* kr = (const char*)&Ks[cur][0] + (s*16+r)*256;
        #pragma unroll
        for (int c=0;c<4;c++){
          short8 kf = *(const short8*)(kr + ((c*64 + g*16) ^ sw));
          aA = MFMA16(qfA[c], kf, aA);
          aB = MFMA16(qfB[c], kf, aB);
        }
        SA[s] = aA; SB[s] = aB;
      }
      __builtin_amdgcn_s_setprio(0);
      // mask + in-lane max only (no cross-lane ops on the common path)
      bool fullA = (kt+63 <= w0A) && (kt >= w0A-496);
      bool fullB = (kt+63 <= w0B) && (kt >= w0B-496);
      float lmA[4], lmB[4];
      if (fullA){
        #pragma unroll
        for (int rr=0;rr<4;rr++)
          lmA[rr] = fmaxf(fmaxf(SA[0][rr],SA[1][rr]), fmaxf(SA[2][rr],SA[3][rr]));
      } else {
        #pragma unroll
        for (int rr=0;rr<4;rr++){
          int baseA = w0A + 4*g + rr - kt;
          float ma = -3e38f;
          #pragma unroll
          for (int s=0;s<4;s++){
            int dd = baseA - s*16 - r;
            float sa = ((unsigned)dd < 512u) ? SA[s][rr] : -3e38f;
            SA[s][rr] = sa;
            ma = fmaxf(ma, sa);
          }
          lmA[rr] = ma;
        }
      }
      if (fullB){
        #pragma unroll
        for (int rr=0;rr<4;rr++)
          lmB[rr] = fmaxf(fmaxf(SB[0][rr],SB[1][rr]), fmaxf(SB[2][rr],SB[3][rr]));
      } else {
        #pragma unroll
        for (int rr=0;rr<4;rr++){
          int baseB = w0B + 4*g + rr - kt;
          float mb_ = -3e38f;
          #pragma unroll
          for (int s=0;s<4;s++){
            int dd = baseB - s*16 - r;
            float sb = ((unsigned)dd < 512u) ? SB[s][rr] : -3e38f;
            SB[s][rr] = sb;
            mb_ = fmaxf(mb_, sb);
          }
          lmB[rr] = mb_;
        }
      }
      // shuffle-free defer-max gate
      bool okA = true, okB = true;
      #pragma unroll
      for (int rr=0;rr<4;rr++){
        okA = okA && (lmA[rr] - mA[rr] <= 8.f);
        okB = okB && (lmB[rr] - mB[rr] <= 8.f);
      }
      if (!__all(okA)){
        float mxA[4];
        #pragma unroll
        for (int rr=0;rr<4;rr++) mxA[rr] = lmA[rr];
        #pragma unroll
        for (int st=1; st<16; st<<=1)
          #pragma unroll
          for (int rr=0;rr<4;rr++)
            mxA[rr] = fmaxf(mxA[rr], __shfl_xor(mxA[rr], st));
        #pragma unroll
        for (int rr=0;rr<4;rr++){
          float mn = fmaxf(mA[rr], mxA[rr]);
          float al = exp2f(mA[rr] - mn);
          mA[rr] = mn;
          lsA[rr] *= al;
          #pragma unroll
          for (int d=0;d<8;d++) accA[d][rr] *= al;
        }
      }
      if (!__all(okB)){
        float mxB[4];
        #pragma unroll
        for (int rr=0;rr<4;rr++) mxB[rr] = lmB[rr];
        #pragma unroll
        for (int st=1; st<16; st<<=1)
          #pragma unroll
          for (int rr=0;rr<4;rr++)
            mxB[rr] = fmaxf(mxB[rr], __shfl_xor(mxB[rr], st));
        #pragma unroll
        for (int rr=0;rr<4;rr++){
          float mn = fmaxf(mB[rr], mxB[rr]);
          float al = exp2f(mB[rr] - mn);
          mB[rr] = mn;
          lsB[rr] *= al;
          #pragma unroll
          for (int d=0;d<8;d++) accB[d][rr] *= al;
        }
      }
      #pragma unroll
      for (int rr=0;rr<4;rr++){
        float psA = 0.f, psB = 0.f;
        #pragma unroll
        for (int s=0;s<4;s++){
          float pa = exp2f(SA[s][rr] - mA[rr]);
          float pb = exp2f(SB[s][rr] - mB[rr]);
          SA[s][rr] = pa; SB[s][rr] = pb;
          psA += pa; psB += pb;
        }
        lsA[rr] += psA;
        lsB[rr] += psB;
      }
      // P relayout via per-wave LDS (A then B; DS ops in-order per wave)
      #pragma unroll
      for (int rr=0;rr<4;rr++)
        #pragma unroll
        for (int s=0;s<4;s++)
          plds[wave][4*g+rr][s*16+r] = f2b(SA[s][rr]);
      short8 pfA0 = *(const short8*)&plds[wave][r][g*8];
      short8 pfA1 = *(const short8*)&plds[wave][r][32 + g*8];
      #pragma unroll
      for (int rr=0;rr<4;rr++)
        #pragma unroll
        for (int s=0;s<4;s++)
          plds[wave][4*g+rr][s*16+r] = f2b(SB[s][rr]);
      short8 pfB0 = *(const short8*)&plds[wave][r][g*8];
      short8 pfB1 = *(const short8*)&plds[wave][r][32 + g*8];
      // PV, shared V fragments from LDS
      __builtin_amdgcn_s_setprio(1);
      #pragma unroll
      for (int d=0;d<8;d++){
        const char* vr = (const char*)&Vs[cur][0] + (d*16+r)*128;
        short8 vf0 = *(const short8*)(vr + ((g*16) ^ sw));
        short8 vf1 = *(const short8*)(vr + ((64 + g*16) ^ sw));
        accA[d] = MFMA16(pfA0, vf0, accA[d]);
        accA[d] = MFMA16(pfA1, vf1, accA[d]);
        accB[d] = MFMA16(pfB0, vf0, accB[d]);
        accB[d] = MFMA16(pfB1, vf1, accB[d]);
      }
      __builtin_amdgcn_s_setprio(0);
    }
    __syncthreads();
    cur ^= 1;
  }

  #pragma unroll
  for (int rr=0;rr<4;rr++){
    float sa = lsA[rr], sb = lsB[rr];
    #pragma unroll
    for (int st=1; st<16; st<<=1){ sa += __shfl_xor(sa, st); sb += __shfl_xor(sb, st); }
    float invA = 1.f/sa, invB = 1.f/sb;
    int iA = w0A + 4*g + rr, iB = w0B + 4*g + rr;
    #pragma unroll
    for (int d=0;d<8;d++){
      y[((size_t)(b*2048)+iA)*2048 + h*128 + d*16 + r] = f2b(accA[d][rr]*invA);
      y[((size_t)(b*2048)+iB)*2048 + h*128 + d*16 + r] = f2b(accB[d][rr]*invB);
    }
  }
}

extern "C" void kernel_launch(void* const* d_in, const int* in_sizes, int n_in,
                              void* d_out, int out_size, void* d_ws, size_t ws_size,
                              hipStream_t stream) {
  const float* x      = (const float*)d_in[0];
  const float* w_attn = (const float*)d_in[1];
  const float* w_proj = (const float*)d_in[2];
  const float* fc     = (const float*)d_in[3];
  float* out = (float*)d_out;
  char* ws = (char*)d_ws;
  unsigned short* xb   = (unsigned short*)(ws);             // 16,777,216
  unsigned short* wtA  = (unsigned short*)(ws + 16777216);  // 12,582,912
  unsigned short* wtP  = (unsigned short*)(ws + 29360128);  //  8,388,608
  unsigned short* qkvb = (unsigned short*)(ws + 37748736);  // 25,165,824
  unsigned short* yb   = (unsigned short*)(ws + 62914560);  // 16,777,216
  unsigned short* kb   = (unsigned short*)(ws + 79691776);  //  4,194,304
  unsigned short* vtb  = (unsigned short*)(ws + 83886080);  //  4,194,304

  k_prep<<<14336, 256, 0, stream>>>(x, w_attn, w_proj, xb, wtA, wtP);
  k_gemm97<1><<<dim3(768), 256, 0, stream>>>(xb, wtA, qkvb, 4096, 3072, 2048, 24);
  k_mid<<<6144, 256, 0, stream>>>(qkvb, fc, kb, vtb);
  k_attn<<<dim3(16,16,2), 256, 0, stream>>>(qkvb, fc, kb, vtb, yb);
  k_gemm97<0><<<dim3(512), 256, 0, stream>>>(yb, wtP, out, 4096, 2048, 2048, 16);
}